// Round 12
// baseline (127.005 us; speedup 1.0000x reference)
//
#include <hip/hip_runtime.h>
#include <hip/hip_bf16.h>

#define NB 8
#define CH 256
#define NN 4096
#define CQK 32
#define LOG2E 1.4426950408889634f

typedef __attribute__((ext_vector_type(4))) float f32x4;
typedef __attribute__((ext_vector_type(8))) short bf16x8;
typedef unsigned short u16;

static __device__ __forceinline__ u16 f2bf(float f) {
  unsigned int u = __float_as_uint(f);
  unsigned int r = (u + 0x7fffu + ((u >> 16) & 1u)) >> 16;
  return (u16)r;
}

// ---------------------------------------------------------------------------
// Kernel 1: weights -> bf16, FRAGMENT-PACKED (contiguous 1KB wave loads).
// ---------------------------------------------------------------------------
__global__ void prep_weights(const float* __restrict__ Wq, const float* __restrict__ bq,
                             const float* __restrict__ Wk, const float* __restrict__ bk,
                             const float* __restrict__ Wv,
                             u16* __restrict__ Wqkf, u16* __restrict__ Wvf,
                             float* __restrict__ bqk) {
  int i = blockIdx.x * 256 + threadIdx.x;   // 65536
  int o = i >> 8, c = i & 255;
  int kk = c >> 5, g2 = (c >> 3) & 3, j = c & 7;
  if (o < 64) {
    float wv = (o < 32) ? Wq[o * 256 + c] * LOG2E : Wk[(o - 32) * 256 + c];
    Wqkf[((((o >> 4) * 8 + kk) * 4 + g2) * 16 + (o & 15)) * 8 + j] = f2bf(wv);
  }
  Wvf[((((o >> 4) * 8 + kk) * 4 + g2) * 16 + (o & 15)) * 8 + j] = f2bf(Wv[i]);
  if (i < 64) bqk[i] = (i < 32) ? bq[i] * LOG2E : bk[i - 32];
}

// ---------------------------------------------------------------------------
// Kernel 2: FUSED transpose + both projections (r11, unchanged — verified).
// ---------------------------------------------------------------------------
__global__ __launch_bounds__(256, 2) void fused_proj(
    const float* __restrict__ x, const u16* __restrict__ Wqkf,
    const u16* __restrict__ Wvf, const float* __restrict__ bqk,
    const float* __restrict__ bv,
    u16* __restrict__ qbuf, u16* __restrict__ kbuf, u16* __restrict__ vbuf) {
  __shared__ __align__(128) char xt[64 * 512];
  const int b = blockIdx.y, n0 = blockIdx.x * 64;
  const int tid = threadIdx.x, w = tid >> 6, l = tid & 63, g = l >> 4, lr = l & 15;
  const f32x4 fzero = {0.f, 0.f, 0.f, 0.f};

  {
    const int nl = l, cl = w;
    const float* xp = x + (size_t)b * CH * NN + n0 + nl;
    char* xrow = xt + nl * 512;
    const int swz = (nl & 15) << 4;
#pragma unroll
    for (int p = 0; p < 32; ++p) {
      const int c = p * 8 + cl * 2;
      float f0 = xp[(size_t)c * NN], f1 = xp[(size_t)(c + 1) * NN];
      unsigned int pk = (unsigned int)f2bf(f0) | ((unsigned int)f2bf(f1) << 16);
      *(unsigned int*)(xrow + ((c * 2) ^ swz)) = pk;
    }
  }
  __syncthreads();

  const int aswz = lr << 4;

  {
    f32x4 acc[4];
#pragma unroll
    for (int ct = 0; ct < 4; ++ct) acc[ct] = fzero;
#pragma unroll
    for (int kk = 0; kk < 8; ++kk) {
      bf16x8 af = *(const bf16x8*)(xt + (w * 16 + lr) * 512 + ((kk * 64 + g * 16) ^ aswz));
#pragma unroll
      for (int ct = 0; ct < 4; ++ct) {
        bf16x8 bf = *(const bf16x8*)(Wqkf + (size_t)(((ct * 8 + kk) * 4 + g) * 16 + lr) * 8);
        acc[ct] = __builtin_amdgcn_mfma_f32_16x16x32_bf16(af, bf, acc[ct], 0, 0, 0);
      }
    }
#pragma unroll
    for (int ct = 0; ct < 4; ++ct) {
      const int col = ct * 16 + lr;
      const float bc = bqk[col];
#pragma unroll
      for (int r = 0; r < 4; ++r) {
        const int row = n0 + w * 16 + g * 4 + r;
        u16 h = f2bf(acc[ct][r] + bc);
        if (col < 32) qbuf[((size_t)(b * NN + row)) * 32 + col] = h;
        else          kbuf[((size_t)(b * NN + row)) * 32 + (col - 32)] = h;
      }
    }
  }

  {
    f32x4 vacc[4][4];
#pragma unroll
    for (int ct = 0; ct < 4; ++ct)
#pragma unroll
      for (int mt = 0; mt < 4; ++mt) vacc[ct][mt] = fzero;
#pragma unroll
    for (int kk = 0; kk < 8; ++kk) {
      bf16x8 bfm[4];
#pragma unroll
      for (int mt = 0; mt < 4; ++mt)
        bfm[mt] = *(const bf16x8*)(xt + (mt * 16 + lr) * 512 + ((kk * 64 + g * 16) ^ aswz));
#pragma unroll
      for (int ct = 0; ct < 4; ++ct) {
        bf16x8 af = *(const bf16x8*)(Wvf + (size_t)((((w * 4 + ct) * 8 + kk) * 4 + g) * 16 + lr) * 8);
#pragma unroll
        for (int mt = 0; mt < 4; ++mt)
          vacc[ct][mt] = __builtin_amdgcn_mfma_f32_16x16x32_bf16(af, bfm[mt], vacc[ct][mt], 0, 0, 0);
      }
    }
#pragma unroll
    for (int ct = 0; ct < 4; ++ct) {
#pragma unroll
      for (int mt = 0; mt < 4; ++mt) {
        const int m = n0 + mt * 16 + lr;
#pragma unroll
        for (int r = 0; r < 4; ++r) {
          const int ch = w * 64 + ct * 16 + g * 4 + r;
          vbuf[((size_t)(b * 128 + (m >> 5)) * 256 + ch) * 32 + (m & 31)] = f2bf(vacc[ct][mt][r] + bv[ch]);
        }
      }
    }
  }
}

// ---------------------------------------------------------------------------
// Kernel 3: fused attention, 128-query blocks, 8 waves.
// QK^T+softmax: wave w owns q-tile w (16 q), full 64-m column (4 MFMA,
//   complete in-wave lsum).
// PV (16x16 MFMA, proven conflict-light reads): wave w = (qg=w>>2, cg=w&3)
//   owns 64 q x 64 ch -> reads only its q-half of P: P-LDS traffic HALVED
//   vs r10/r11 (the dominant per-iter cost), read slots uniform (g^(lr&7)).
// V: 8 frags/iter; m-half-1 prefetched pre-barrier, next tile's m-half-0
//   prefetched between post-barrier MFMA groups. K/V global loads stay in
//   flight across the lgkm-only barrier. setprio on PV cluster.
// ---------------------------------------------------------------------------
#define KLOAD(t, sub) (*(const bf16x8*)(kp + (size_t)((((t) & 63) * 64) + (sub) * 16) * 32))
#define VLOAD(mg, ct) (*(const bf16x8*)(vp + (size_t)((mg) & 127) * 8192 + (ct) * 512))

#define EXPP(S, PW, MASK) {                                                                   \
  float e0 = __builtin_amdgcn_exp2f(S[0]);                                                    \
  float e1 = __builtin_amdgcn_exp2f(S[1]);                                                    \
  float e2 = __builtin_amdgcn_exp2f(S[2]);                                                    \
  float e3 = __builtin_amdgcn_exp2f(S[3]);                                                    \
  lsum += (MASK) * ((e0 + e1) + (e2 + e3));                                                   \
  PW.x = __builtin_amdgcn_perm(__float_as_uint(e1) + 0x8000u, __float_as_uint(e0) + 0x8000u, 0x07060302u); \
  PW.y = __builtin_amdgcn_perm(__float_as_uint(e3) + 0x8000u, __float_as_uint(e2) + 0x8000u, 0x07060302u); \
}

#define PBAR() do {                                  \
  __builtin_amdgcn_sched_barrier(0);                 \
  asm volatile("s_waitcnt lgkmcnt(0)");              \
  __builtin_amdgcn_s_barrier();                      \
  __builtin_amdgcn_sched_barrier(0);                 \
} while (0)

// post-barrier: write P(t+1) -> Pb[BUF^1]; PV over m-half0 (vA) then m-half1
// (vB) from Pb[BUF]; vA reloaded with next tile's m-half0 between the groups.
#define PVPH(BUF, NEXTMG) {                                                                   \
  const char* prb = (const char*)Pb + (BUF) * 16384;                                          \
  char* pdst = (char*)Pb + ((BUF) ^ 1) * 16384 + prow * 128;                                  \
  *(uint2*)(pdst + ((0 * 32 + g * 8) ^ wswz)) = pw0;                                          \
  *(uint2*)(pdst + ((1 * 32 + g * 8) ^ wswz)) = pw1;                                          \
  *(uint2*)(pdst + ((2 * 32 + g * 8) ^ wswz)) = pw2;                                          \
  *(uint2*)(pdst + ((3 * 32 + g * 8) ^ wswz)) = pw3;                                          \
  __builtin_amdgcn_s_setprio(1);                                                              \
  _Pragma("unroll")                                                                           \
  for (int nt = 0; nt < 4; ++nt) {                                                            \
    const int row = qg * 64 + nt * 16 + lr;                                                   \
    const int rs = (row & 7) << 4;                                                            \
    bf16x8 pa = *(const bf16x8*)(prb + row * 128 + ((g * 16) ^ rs));                          \
    oacc[nt][0] = __builtin_amdgcn_mfma_f32_16x16x32_bf16(vA0, pa, oacc[nt][0], 0, 0, 0);     \
    oacc[nt][1] = __builtin_amdgcn_mfma_f32_16x16x32_bf16(vA1, pa, oacc[nt][1], 0, 0, 0);     \
    oacc[nt][2] = __builtin_amdgcn_mfma_f32_16x16x32_bf16(vA2, pa, oacc[nt][2], 0, 0, 0);     \
    oacc[nt][3] = __builtin_amdgcn_mfma_f32_16x16x32_bf16(vA3, pa, oacc[nt][3], 0, 0, 0);     \
  }                                                                                           \
  vA0 = VLOAD(NEXTMG, 0); vA1 = VLOAD(NEXTMG, 1);                                             \
  vA2 = VLOAD(NEXTMG, 2); vA3 = VLOAD(NEXTMG, 3);                                             \
  _Pragma("unroll")                                                                           \
  for (int nt = 0; nt < 4; ++nt) {                                                            \
    const int row = qg * 64 + nt * 16 + lr;                                                   \
    const int rs = (row & 7) << 4;                                                            \
    bf16x8 pa = *(const bf16x8*)(prb + row * 128 + ((64 + g * 16) ^ rs));                     \
    oacc[nt][0] = __builtin_amdgcn_mfma_f32_16x16x32_bf16(vB0, pa, oacc[nt][0], 0, 0, 0);     \
    oacc[nt][1] = __builtin_amdgcn_mfma_f32_16x16x32_bf16(vB1, pa, oacc[nt][1], 0, 0, 0);     \
    oacc[nt][2] = __builtin_amdgcn_mfma_f32_16x16x32_bf16(vB2, pa, oacc[nt][2], 0, 0, 0);     \
    oacc[nt][3] = __builtin_amdgcn_mfma_f32_16x16x32_bf16(vB3, pa, oacc[nt][3], 0, 0, 0);     \
  }                                                                                           \
  __builtin_amdgcn_s_setprio(0);                                                              \
}

__global__ __launch_bounds__(512, 2) void attn_fused(
    const u16* __restrict__ qb, const u16* __restrict__ kbuf,
    const u16* __restrict__ vbuf, const float* __restrict__ x,
    const float* __restrict__ gamma_p, float* __restrict__ out) {
  __shared__ __align__(128) char Pb[2][128 * 128];
  __shared__ float lsum_s[128];

  const int b = blockIdx.x;          // batch -> XCD pinning
  const int n0 = blockIdx.y * 128;
  const int tid = threadIdx.x, w = tid >> 6, l = tid & 63, g = l >> 4, lr = l & 15;
  const int qg = w >> 2, cg = w & 3;
  const float gamma0 = gamma_p[0];
  const f32x4 fzero = {0.f, 0.f, 0.f, 0.f};

  bf16x8 qf = *(const bf16x8*)(qb + ((size_t)b * NN + n0 + w * 16 + lr) * 32 + g * 8);

  const u16* kp = kbuf + (size_t)b * (NN * 32) + (size_t)lr * 32 + g * 8;
  const u16* vp = vbuf + (size_t)b * 1048576 + (size_t)(cg * 64 + lr) * 32 + g * 8;

  f32x4 oacc[4][4];
#pragma unroll
  for (int nt = 0; nt < 4; ++nt)
#pragma unroll
    for (int ct = 0; ct < 4; ++ct) oacc[nt][ct] = fzero;
  float lsum = 0.f;

  const int prow = w * 16 + lr;
  const int wswz = (prow & 7) << 4;

  // ---- prologue: K(0), K(1), V(0,mh0); P(0) -> Pb[0] ----
  bf16x8 kA0 = KLOAD(0, 0), kA1 = KLOAD(0, 1), kA2 = KLOAD(0, 2), kA3 = KLOAD(0, 3);
  bf16x8 vA0 = VLOAD(0, 0), vA1 = VLOAD(0, 1), vA2 = VLOAD(0, 2), vA3 = VLOAD(0, 3);
  bf16x8 kB0 = KLOAD(1, 0), kB1 = KLOAD(1, 1), kB2 = KLOAD(1, 2), kB3 = KLOAD(1, 3);
  bf16x8 vB0, vB1, vB2, vB3;
  uint2 pw0, pw1, pw2, pw3;
  {
    f32x4 s0 = __builtin_amdgcn_mfma_f32_16x16x32_bf16(kA0, qf, fzero, 0, 0, 0);
    f32x4 s1 = __builtin_amdgcn_mfma_f32_16x16x32_bf16(kA1, qf, fzero, 0, 0, 0);
    f32x4 s2 = __builtin_amdgcn_mfma_f32_16x16x32_bf16(kA2, qf, fzero, 0, 0, 0);
    f32x4 s3 = __builtin_amdgcn_mfma_f32_16x16x32_bf16(kA3, qf, fzero, 0, 0, 0);
    EXPP(s0, pw0, 1.0f); EXPP(s1, pw1, 1.0f); EXPP(s2, pw2, 1.0f); EXPP(s3, pw3, 1.0f);
    char* pdst = (char*)Pb + prow * 128;
    *(uint2*)(pdst + ((0 * 32 + g * 8) ^ wswz)) = pw0;
    *(uint2*)(pdst + ((1 * 32 + g * 8) ^ wswz)) = pw1;
    *(uint2*)(pdst + ((2 * 32 + g * 8) ^ wswz)) = pw2;
    *(uint2*)(pdst + ((3 * 32 + g * 8) ^ wswz)) = pw3;
  }

  for (int it2 = 0; it2 < 32; ++it2) {
    // ===== phase even: t = 2*it2; consume P(t)/V(t); prepare P(t+1) =====
    {
      const int tn = 2 * it2 + 1;
      f32x4 s0 = __builtin_amdgcn_mfma_f32_16x16x32_bf16(kB0, qf, fzero, 0, 0, 0);
      f32x4 s1 = __builtin_amdgcn_mfma_f32_16x16x32_bf16(kB1, qf, fzero, 0, 0, 0);
      f32x4 s2 = __builtin_amdgcn_mfma_f32_16x16x32_bf16(kB2, qf, fzero, 0, 0, 0);
      f32x4 s3 = __builtin_amdgcn_mfma_f32_16x16x32_bf16(kB3, qf, fzero, 0, 0, 0);
      kA0 = KLOAD(tn + 1, 0); kA1 = KLOAD(tn + 1, 1); kA2 = KLOAD(tn + 1, 2); kA3 = KLOAD(tn + 1, 3);
      vB0 = VLOAD(4 * it2 + 1, 0); vB1 = VLOAD(4 * it2 + 1, 1);
      vB2 = VLOAD(4 * it2 + 1, 2); vB3 = VLOAD(4 * it2 + 1, 3);
      EXPP(s0, pw0, 1.0f); EXPP(s1, pw1, 1.0f); EXPP(s2, pw2, 1.0f); EXPP(s3, pw3, 1.0f);
      PBAR();
      PVPH(0, 4 * it2 + 2);
    }
    // ===== phase odd: t = 2*it2+1 =====
    {
      const int tn = 2 * it2 + 2;
      const float tmask = (it2 < 31) ? 1.0f : 0.0f;  // exclude wrapped tile 64
      f32x4 s0 = __builtin_amdgcn_mfma_f32_16x16x32_bf16(kA0, qf, fzero, 0, 0, 0);
      f32x4 s1 = __builtin_amdgcn_mfma_f32_16x16x32_bf16(kA1, qf, fzero, 0, 0, 0);
      f32x4 s2 = __builtin_amdgcn_mfma_f32_16x16x32_bf16(kA2, qf, fzero, 0, 0, 0);
      f32x4 s3 = __builtin_amdgcn_mfma_f32_16x16x32_bf16(kA3, qf, fzero, 0, 0, 0);
      kB0 = KLOAD(tn + 1, 0); kB1 = KLOAD(tn + 1, 1); kB2 = KLOAD(tn + 1, 2); kB3 = KLOAD(tn + 1, 3);
      vB0 = VLOAD(4 * it2 + 3, 0); vB1 = VLOAD(4 * it2 + 3, 1);
      vB2 = VLOAD(4 * it2 + 3, 2); vB3 = VLOAD(4 * it2 + 3, 3);
      EXPP(s0, pw0, tmask); EXPP(s1, pw1, tmask); EXPP(s2, pw2, tmask); EXPP(s3, pw3, tmask);
      PBAR();
      PVPH(1, 4 * it2 + 4);
    }
  }

  // ---- epilogue: share lsum, normalize, gamma*O + x ----
  lsum += __shfl_xor(lsum, 16);
  lsum += __shfl_xor(lsum, 32);
  if (l < 16) lsum_s[w * 16 + lr] = lsum;
  __syncthreads();

  const size_t bbase = (size_t)b * CH * NN;
#pragma unroll
  for (int nt = 0; nt < 4; ++nt) {
    const int q = qg * 64 + nt * 16 + lr;
    const float linv = 1.f / lsum_s[q];
    const int n = n0 + q;
#pragma unroll
    for (int ct = 0; ct < 4; ++ct) {
      const int cbase = cg * 64 + ct * 16 + g * 4;
#pragma unroll
      for (int r = 0; r < 4; ++r) {
        const size_t off = bbase + (size_t)(cbase + r) * NN + n;
        out[off] = gamma0 * (oacc[nt][ct][r] * linv) + x[off];
      }
    }
  }
}

// ---------------------------------------------------------------------------
extern "C" void kernel_launch(void* const* d_in, const int* in_sizes, int n_in,
                              void* d_out, int out_size, void* d_ws, size_t ws_size,
                              hipStream_t stream) {
  const float* x     = (const float*)d_in[0];
  const float* Wq    = (const float*)d_in[1];
  const float* bq    = (const float*)d_in[2];
  const float* Wk    = (const float*)d_in[3];
  const float* bk    = (const float*)d_in[4];
  const float* Wv    = (const float*)d_in[5];
  const float* bv    = (const float*)d_in[6];
  const float* gamma = (const float*)d_in[7];
  float* out = (float*)d_out;

  char* ws = (char*)d_ws;
  u16*   qbuf = (u16*)(ws);                 // [B,N,32] packed      2,097,152 B
  u16*   kbuf = (u16*)(ws + 2097152);       // [B,N,32] packed      2,097,152 B
  u16*   vbuf = (u16*)(ws + 4194304);       // v fragments         16,777,216 B
  u16*   Wqkf = (u16*)(ws + 20971520);      // packed frags            32,768 B
  u16*   Wvf  = (u16*)(ws + 21004288);      // packed frags           131,072 B
  float* bqk  = (float*)(ws + 21135360);    // [64] f32                   256 B

  prep_weights<<<256, 256, 0, stream>>>(Wq, bq, Wk, bk, Wv, Wqkf, Wvf, bqk);
  fused_proj<<<dim3(64, 8), 256, 0, stream>>>(x, Wqkf, Wvf, bqk, bv, qbuf, kbuf, vbuf);
  attn_fused<<<dim3(8, 32), 512, 0, stream>>>(qbuf, kbuf, vbuf, x, gamma, out);
}

// Round 13
// 125.266 us; speedup vs baseline: 1.0139x; 1.0139x over previous
//
#include <hip/hip_runtime.h>
#include <hip/hip_bf16.h>

#define NB 8
#define CH 256
#define NN 4096
#define CQK 32
#define LOG2E 1.4426950408889634f

typedef __attribute__((ext_vector_type(4))) float f32x4;
typedef __attribute__((ext_vector_type(8))) short bf16x8;
typedef unsigned short u16;

static __device__ __forceinline__ u16 f2bf(float f) {
  unsigned int u = __float_as_uint(f);
  unsigned int r = (u + 0x7fffu + ((u >> 16) & 1u)) >> 16;
  return (u16)r;
}

// ---------------------------------------------------------------------------
// Kernel 1: weights -> bf16, FRAGMENT-PACKED (contiguous 1KB wave loads).
// ---------------------------------------------------------------------------
__global__ void prep_weights(const float* __restrict__ Wq, const float* __restrict__ bq,
                             const float* __restrict__ Wk, const float* __restrict__ bk,
                             const float* __restrict__ Wv,
                             u16* __restrict__ Wqkf, u16* __restrict__ Wvf,
                             float* __restrict__ bqk) {
  int i = blockIdx.x * 256 + threadIdx.x;   // 65536
  int o = i >> 8, c = i & 255;
  int kk = c >> 5, g2 = (c >> 3) & 3, j = c & 7;
  if (o < 64) {
    float wv = (o < 32) ? Wq[o * 256 + c] * LOG2E : Wk[(o - 32) * 256 + c];
    Wqkf[((((o >> 4) * 8 + kk) * 4 + g2) * 16 + (o & 15)) * 8 + j] = f2bf(wv);
  }
  Wvf[((((o >> 4) * 8 + kk) * 4 + g2) * 16 + (o & 15)) * 8 + j] = f2bf(Wv[i]);
  if (i < 64) bqk[i] = (i < 32) ? bq[i] * LOG2E : bk[i - 32];
}

// ---------------------------------------------------------------------------
// Kernel 2: FUSED transpose + both projections (r11, unchanged — verified).
// ---------------------------------------------------------------------------
__global__ __launch_bounds__(256, 2) void fused_proj(
    const float* __restrict__ x, const u16* __restrict__ Wqkf,
    const u16* __restrict__ Wvf, const float* __restrict__ bqk,
    const float* __restrict__ bv,
    u16* __restrict__ qbuf, u16* __restrict__ kbuf, u16* __restrict__ vbuf) {
  __shared__ __align__(128) char xt[64 * 512];
  const int b = blockIdx.y, n0 = blockIdx.x * 64;
  const int tid = threadIdx.x, w = tid >> 6, l = tid & 63, g = l >> 4, lr = l & 15;
  const f32x4 fzero = {0.f, 0.f, 0.f, 0.f};

  {
    const int nl = l, cl = w;
    const float* xp = x + (size_t)b * CH * NN + n0 + nl;
    char* xrow = xt + nl * 512;
    const int swz = (nl & 15) << 4;
#pragma unroll
    for (int p = 0; p < 32; ++p) {
      const int c = p * 8 + cl * 2;
      float f0 = xp[(size_t)c * NN], f1 = xp[(size_t)(c + 1) * NN];
      unsigned int pk = (unsigned int)f2bf(f0) | ((unsigned int)f2bf(f1) << 16);
      *(unsigned int*)(xrow + ((c * 2) ^ swz)) = pk;
    }
  }
  __syncthreads();

  const int aswz = lr << 4;

  {
    f32x4 acc[4];
#pragma unroll
    for (int ct = 0; ct < 4; ++ct) acc[ct] = fzero;
#pragma unroll
    for (int kk = 0; kk < 8; ++kk) {
      bf16x8 af = *(const bf16x8*)(xt + (w * 16 + lr) * 512 + ((kk * 64 + g * 16) ^ aswz));
#pragma unroll
      for (int ct = 0; ct < 4; ++ct) {
        bf16x8 bf = *(const bf16x8*)(Wqkf + (size_t)(((ct * 8 + kk) * 4 + g) * 16 + lr) * 8);
        acc[ct] = __builtin_amdgcn_mfma_f32_16x16x32_bf16(af, bf, acc[ct], 0, 0, 0);
      }
    }
#pragma unroll
    for (int ct = 0; ct < 4; ++ct) {
      const int col = ct * 16 + lr;
      const float bc = bqk[col];
#pragma unroll
      for (int r = 0; r < 4; ++r) {
        const int row = n0 + w * 16 + g * 4 + r;
        u16 h = f2bf(acc[ct][r] + bc);
        if (col < 32) qbuf[((size_t)(b * NN + row)) * 32 + col] = h;
        else          kbuf[((size_t)(b * NN + row)) * 32 + (col - 32)] = h;
      }
    }
  }

  {
    f32x4 vacc[4][4];
#pragma unroll
    for (int ct = 0; ct < 4; ++ct)
#pragma unroll
      for (int mt = 0; mt < 4; ++mt) vacc[ct][mt] = fzero;
#pragma unroll
    for (int kk = 0; kk < 8; ++kk) {
      bf16x8 bfm[4];
#pragma unroll
      for (int mt = 0; mt < 4; ++mt)
        bfm[mt] = *(const bf16x8*)(xt + (mt * 16 + lr) * 512 + ((kk * 64 + g * 16) ^ aswz));
#pragma unroll
      for (int ct = 0; ct < 4; ++ct) {
        bf16x8 af = *(const bf16x8*)(Wvf + (size_t)((((w * 4 + ct) * 8 + kk) * 4 + g) * 16 + lr) * 8);
#pragma unroll
        for (int mt = 0; mt < 4; ++mt)
          vacc[ct][mt] = __builtin_amdgcn_mfma_f32_16x16x32_bf16(af, bfm[mt], vacc[ct][mt], 0, 0, 0);
      }
    }
#pragma unroll
    for (int ct = 0; ct < 4; ++ct) {
#pragma unroll
      for (int mt = 0; mt < 4; ++mt) {
        const int m = n0 + mt * 16 + lr;
#pragma unroll
        for (int r = 0; r < 4; ++r) {
          const int ch = w * 64 + ct * 16 + g * 4 + r;
          vbuf[((size_t)(b * 128 + (m >> 5)) * 256 + ch) * 32 + (m & 31)] = f2bf(vacc[ct][mt][r] + bv[ch]);
        }
      }
    }
  }
}

// ---------------------------------------------------------------------------
// Kernel 3: fused attention. 4-wave blocks, each owning 128 q x 128 ch
// (ch-half by blockIdx.z) -> 2 INDEPENDENT blocks per CU with decoupled
// barrier schedules (attacks r10's lockstep: one block's VALU burst overlaps
// the other's MFMA/LDS burst). Per-wave dataflow = r10 (best measured):
//   QK^T+softmax for TWO 16-q tiles (w, w+4): 8 MFMA + 32 exp (P redundant
//   per ch-half, +11% MFMA - cheap).
//   PV: 32ch x 128q, 32 MFMA, reads whole 128-row P tile (16 b128).
// P software-pipelined across the lgkm-only barrier; setprio on PV cluster.
// ---------------------------------------------------------------------------
#define KLOAD(t, sub) (*(const bf16x8*)(kp + (size_t)((((t) & 63) * 64) + (sub) * 16) * 32))
#define VLOAD(mg, ct) (*(const bf16x8*)(vp + (size_t)((mg) & 127) * 8192 + (ct) * 512))

#define EXPP(S, PW, MASK, LS) {                                                               \
  float e0 = __builtin_amdgcn_exp2f(S[0]);                                                    \
  float e1 = __builtin_amdgcn_exp2f(S[1]);                                                    \
  float e2 = __builtin_amdgcn_exp2f(S[2]);                                                    \
  float e3 = __builtin_amdgcn_exp2f(S[3]);                                                    \
  LS += (MASK) * ((e0 + e1) + (e2 + e3));                                                     \
  PW.x = __builtin_amdgcn_perm(__float_as_uint(e1) + 0x8000u, __float_as_uint(e0) + 0x8000u, 0x07060302u); \
  PW.y = __builtin_amdgcn_perm(__float_as_uint(e3) + 0x8000u, __float_as_uint(e2) + 0x8000u, 0x07060302u); \
}

#define PBAR() do {                                  \
  __builtin_amdgcn_sched_barrier(0);                 \
  asm volatile("s_waitcnt lgkmcnt(0)");              \
  __builtin_amdgcn_s_barrier();                      \
  __builtin_amdgcn_sched_barrier(0);                 \
} while (0)

// post-barrier: write P(t+1) (both q-tiles) -> Pb[BUF^1]; 32 PV MFMA from
// Pb[BUF] over all 128 rows with V regs (V0/V1 = m-grp even ch-sub 0/1,
// V2/V3 = m-grp odd).
#define PVPHASE(BUF, V0, V1, V2, V3) {                                                        \
  const char* prb = (const char*)Pb + (BUF) * 16384;                                          \
  char* pdst = (char*)Pb + ((BUF) ^ 1) * 16384 + prow0 * 128;                                 \
  *(uint2*)(pdst + ((0 * 32 + g * 8) ^ wswz)) = pw0;                                          \
  *(uint2*)(pdst + ((1 * 32 + g * 8) ^ wswz)) = pw1;                                          \
  *(uint2*)(pdst + ((2 * 32 + g * 8) ^ wswz)) = pw2;                                          \
  *(uint2*)(pdst + ((3 * 32 + g * 8) ^ wswz)) = pw3;                                          \
  pdst += 64 * 128;                                                                           \
  *(uint2*)(pdst + ((0 * 32 + g * 8) ^ wswz)) = pw4;                                          \
  *(uint2*)(pdst + ((1 * 32 + g * 8) ^ wswz)) = pw5;                                          \
  *(uint2*)(pdst + ((2 * 32 + g * 8) ^ wswz)) = pw6;                                          \
  *(uint2*)(pdst + ((3 * 32 + g * 8) ^ wswz)) = pw7;                                          \
  __builtin_amdgcn_s_setprio(1);                                                              \
  _Pragma("unroll")                                                                           \
  for (int nt = 0; nt < 8; ++nt) {                                                            \
    const int row = nt * 16 + lr;                                                             \
    const int rs = (row & 7) << 4;                                                            \
    bf16x8 pa0 = *(const bf16x8*)(prb + row * 128 + ((g * 16) ^ rs));                         \
    bf16x8 pa1 = *(const bf16x8*)(prb + row * 128 + ((64 + g * 16) ^ rs));                    \
    oacc[nt][0] = __builtin_amdgcn_mfma_f32_16x16x32_bf16(V0, pa0, oacc[nt][0], 0, 0, 0);     \
    oacc[nt][1] = __builtin_amdgcn_mfma_f32_16x16x32_bf16(V1, pa0, oacc[nt][1], 0, 0, 0);     \
    oacc[nt][0] = __builtin_amdgcn_mfma_f32_16x16x32_bf16(V2, pa1, oacc[nt][0], 0, 0, 0);     \
    oacc[nt][1] = __builtin_amdgcn_mfma_f32_16x16x32_bf16(V3, pa1, oacc[nt][1], 0, 0, 0);     \
  }                                                                                           \
  __builtin_amdgcn_s_setprio(0);                                                              \
}

__global__ __launch_bounds__(256, 2) void attn_fused(
    const u16* __restrict__ qb, const u16* __restrict__ kbuf,
    const u16* __restrict__ vbuf, const float* __restrict__ x,
    const float* __restrict__ gamma_p, float* __restrict__ out) {
  __shared__ __align__(128) char Pb[2][128 * 128];
  __shared__ float lsum_s[128];

  const int b = blockIdx.x;          // batch -> XCD pinning
  const int n0 = blockIdx.y * 128;
  const int chh = blockIdx.z;        // channel half (0/1)
  const int tid = threadIdx.x, w = tid >> 6, l = tid & 63, g = l >> 4, lr = l & 15;
  const float gamma0 = gamma_p[0];
  const f32x4 fzero = {0.f, 0.f, 0.f, 0.f};

  // two q fragments: q-tiles w and w+4
  bf16x8 qf0 = *(const bf16x8*)(qb + ((size_t)b * NN + n0 + w * 16 + lr) * 32 + g * 8);
  bf16x8 qf1 = *(const bf16x8*)(qb + ((size_t)b * NN + n0 + 64 + w * 16 + lr) * 32 + g * 8);

  const u16* kp = kbuf + (size_t)b * (NN * 32) + (size_t)lr * 32 + g * 8;
  const u16* vp = vbuf + (size_t)b * 1048576 + (size_t)(chh * 128 + w * 32 + lr) * 32 + g * 8;

  f32x4 oacc[8][2];
#pragma unroll
  for (int nt = 0; nt < 8; ++nt)
#pragma unroll
    for (int ct = 0; ct < 2; ++ct) oacc[nt][ct] = fzero;
  float lsum0 = 0.f, lsum1 = 0.f;

  const int prow0 = w * 16 + lr;
  const int wswz = (prow0 & 7) << 4;   // (prow0+64)&7 identical

  // ---- prologue: K(0), K(1), V(0); P(0) for both q-tiles -> Pb[0] ----
  bf16x8 kA0 = KLOAD(0, 0), kA1 = KLOAD(0, 1), kA2 = KLOAD(0, 2), kA3 = KLOAD(0, 3);
  bf16x8 vA0 = VLOAD(0, 0), vA1 = VLOAD(0, 1), vA2 = VLOAD(1, 0), vA3 = VLOAD(1, 1);
  bf16x8 kB0 = KLOAD(1, 0), kB1 = KLOAD(1, 1), kB2 = KLOAD(1, 2), kB3 = KLOAD(1, 3);
  bf16x8 vB0, vB1, vB2, vB3;
  uint2 pw0, pw1, pw2, pw3, pw4, pw5, pw6, pw7;
  {
    f32x4 s0 = __builtin_amdgcn_mfma_f32_16x16x32_bf16(kA0, qf0, fzero, 0, 0, 0);
    f32x4 s1 = __builtin_amdgcn_mfma_f32_16x16x32_bf16(kA1, qf0, fzero, 0, 0, 0);
    f32x4 s2 = __builtin_amdgcn_mfma_f32_16x16x32_bf16(kA2, qf0, fzero, 0, 0, 0);
    f32x4 s3 = __builtin_amdgcn_mfma_f32_16x16x32_bf16(kA3, qf0, fzero, 0, 0, 0);
    f32x4 s4 = __builtin_amdgcn_mfma_f32_16x16x32_bf16(kA0, qf1, fzero, 0, 0, 0);
    f32x4 s5 = __builtin_amdgcn_mfma_f32_16x16x32_bf16(kA1, qf1, fzero, 0, 0, 0);
    f32x4 s6 = __builtin_amdgcn_mfma_f32_16x16x32_bf16(kA2, qf1, fzero, 0, 0, 0);
    f32x4 s7 = __builtin_amdgcn_mfma_f32_16x16x32_bf16(kA3, qf1, fzero, 0, 0, 0);
    EXPP(s0, pw0, 1.0f, lsum0); EXPP(s1, pw1, 1.0f, lsum0);
    EXPP(s2, pw2, 1.0f, lsum0); EXPP(s3, pw3, 1.0f, lsum0);
    EXPP(s4, pw4, 1.0f, lsum1); EXPP(s5, pw5, 1.0f, lsum1);
    EXPP(s6, pw6, 1.0f, lsum1); EXPP(s7, pw7, 1.0f, lsum1);
    char* pdst = (char*)Pb + prow0 * 128;
    *(uint2*)(pdst + ((0 * 32 + g * 8) ^ wswz)) = pw0;
    *(uint2*)(pdst + ((1 * 32 + g * 8) ^ wswz)) = pw1;
    *(uint2*)(pdst + ((2 * 32 + g * 8) ^ wswz)) = pw2;
    *(uint2*)(pdst + ((3 * 32 + g * 8) ^ wswz)) = pw3;
    pdst += 64 * 128;
    *(uint2*)(pdst + ((0 * 32 + g * 8) ^ wswz)) = pw4;
    *(uint2*)(pdst + ((1 * 32 + g * 8) ^ wswz)) = pw5;
    *(uint2*)(pdst + ((2 * 32 + g * 8) ^ wswz)) = pw6;
    *(uint2*)(pdst + ((3 * 32 + g * 8) ^ wswz)) = pw7;
  }

  for (int it2 = 0; it2 < 32; ++it2) {
    // ===== phase even: consume tile 2*it2; prepare 2*it2+1 =====
    {
      const int tn = 2 * it2 + 1;
      f32x4 s0 = __builtin_amdgcn_mfma_f32_16x16x32_bf16(kB0, qf0, fzero, 0, 0, 0);
      f32x4 s1 = __builtin_amdgcn_mfma_f32_16x16x32_bf16(kB1, qf0, fzero, 0, 0, 0);
      f32x4 s2 = __builtin_amdgcn_mfma_f32_16x16x32_bf16(kB2, qf0, fzero, 0, 0, 0);
      f32x4 s3 = __builtin_amdgcn_mfma_f32_16x16x32_bf16(kB3, qf0, fzero, 0, 0, 0);
      f32x4 s4 = __builtin_amdgcn_mfma_f32_16x16x32_bf16(kB0, qf1, fzero, 0, 0, 0);
      f32x4 s5 = __builtin_amdgcn_mfma_f32_16x16x32_bf16(kB1, qf1, fzero, 0, 0, 0);
      f32x4 s6 = __builtin_amdgcn_mfma_f32_16x16x32_bf16(kB2, qf1, fzero, 0, 0, 0);
      f32x4 s7 = __builtin_amdgcn_mfma_f32_16x16x32_bf16(kB3, qf1, fzero, 0, 0, 0);
      kA0 = KLOAD(tn + 1, 0); kA1 = KLOAD(tn + 1, 1); kA2 = KLOAD(tn + 1, 2); kA3 = KLOAD(tn + 1, 3);
      vB0 = VLOAD(2 * tn, 0); vB1 = VLOAD(2 * tn, 1);
      vB2 = VLOAD(2 * tn + 1, 0); vB3 = VLOAD(2 * tn + 1, 1);
      EXPP(s0, pw0, 1.0f, lsum0); EXPP(s1, pw1, 1.0f, lsum0);
      EXPP(s2, pw2, 1.0f, lsum0); EXPP(s3, pw3, 1.0f, lsum0);
      EXPP(s4, pw4, 1.0f, lsum1); EXPP(s5, pw5, 1.0f, lsum1);
      EXPP(s6, pw6, 1.0f, lsum1); EXPP(s7, pw7, 1.0f, lsum1);
      PBAR();
      PVPHASE(0, vA0, vA1, vA2, vA3);
    }
    // ===== phase odd: consume tile 2*it2+1; prepare 2*it2+2 =====
    {
      const int tn = 2 * it2 + 2;
      const float tmask = (it2 < 31) ? 1.0f : 0.0f;  // exclude wrapped tile 64
      f32x4 s0 = __builtin_amdgcn_mfma_f32_16x16x32_bf16(kA0, qf0, fzero, 0, 0, 0);
      f32x4 s1 = __builtin_amdgcn_mfma_f32_16x16x32_bf16(kA1, qf0, fzero, 0, 0, 0);
      f32x4 s2 = __builtin_amdgcn_mfma_f32_16x16x32_bf16(kA2, qf0, fzero, 0, 0, 0);
      f32x4 s3 = __builtin_amdgcn_mfma_f32_16x16x32_bf16(kA3, qf0, fzero, 0, 0, 0);
      f32x4 s4 = __builtin_amdgcn_mfma_f32_16x16x32_bf16(kA0, qf1, fzero, 0, 0, 0);
      f32x4 s5 = __builtin_amdgcn_mfma_f32_16x16x32_bf16(kA1, qf1, fzero, 0, 0, 0);
      f32x4 s6 = __builtin_amdgcn_mfma_f32_16x16x32_bf16(kA2, qf1, fzero, 0, 0, 0);
      f32x4 s7 = __builtin_amdgcn_mfma_f32_16x16x32_bf16(kA3, qf1, fzero, 0, 0, 0);
      kB0 = KLOAD(tn + 1, 0); kB1 = KLOAD(tn + 1, 1); kB2 = KLOAD(tn + 1, 2); kB3 = KLOAD(tn + 1, 3);
      vA0 = VLOAD(2 * tn, 0); vA1 = VLOAD(2 * tn, 1);
      vA2 = VLOAD(2 * tn + 1, 0); vA3 = VLOAD(2 * tn + 1, 1);
      EXPP(s0, pw0, tmask, lsum0); EXPP(s1, pw1, tmask, lsum0);
      EXPP(s2, pw2, tmask, lsum0); EXPP(s3, pw3, tmask, lsum0);
      EXPP(s4, pw4, tmask, lsum1); EXPP(s5, pw5, tmask, lsum1);
      EXPP(s6, pw6, tmask, lsum1); EXPP(s7, pw7, tmask, lsum1);
      PBAR();
      PVPHASE(1, vB0, vB1, vB2, vB3);
    }
  }

  // ---- epilogue: share lsums, normalize, gamma*O + x ----
  lsum0 += __shfl_xor(lsum0, 16);
  lsum0 += __shfl_xor(lsum0, 32);
  lsum1 += __shfl_xor(lsum1, 16);
  lsum1 += __shfl_xor(lsum1, 32);
  if (l < 16) {
    lsum_s[w * 16 + lr] = lsum0;
    lsum_s[64 + w * 16 + lr] = lsum1;
  }
  __syncthreads();

  const size_t bbase = (size_t)b * CH * NN;
#pragma unroll
  for (int nt = 0; nt < 8; ++nt) {
    const int q = nt * 16 + lr;
    const float linv = 1.f / lsum_s[q];
    const int n = n0 + q;
#pragma unroll
    for (int ct = 0; ct < 2; ++ct) {
      const int cbase = chh * 128 + w * 32 + ct * 16 + g * 4;
#pragma unroll
      for (int r = 0; r < 4; ++r) {
        const size_t off = bbase + (size_t)(cbase + r) * NN + n;
        out[off] = gamma0 * (oacc[nt][ct][r] * linv) + x[off];
      }
    }
  }
}

// ---------------------------------------------------------------------------
extern "C" void kernel_launch(void* const* d_in, const int* in_sizes, int n_in,
                              void* d_out, int out_size, void* d_ws, size_t ws_size,
                              hipStream_t stream) {
  const float* x     = (const float*)d_in[0];
  const float* Wq    = (const float*)d_in[1];
  const float* bq    = (const float*)d_in[2];
  const float* Wk    = (const float*)d_in[3];
  const float* bk    = (const float*)d_in[4];
  const float* Wv    = (const float*)d_in[5];
  const float* bv    = (const float*)d_in[6];
  const float* gamma = (const float*)d_in[7];
  float* out = (float*)d_out;

  char* ws = (char*)d_ws;
  u16*   qbuf = (u16*)(ws);                 // [B,N,32] packed      2,097,152 B
  u16*   kbuf = (u16*)(ws + 2097152);       // [B,N,32] packed      2,097,152 B
  u16*   vbuf = (u16*)(ws + 4194304);       // v fragments         16,777,216 B
  u16*   Wqkf = (u16*)(ws + 20971520);      // packed frags            32,768 B
  u16*   Wvf  = (u16*)(ws + 21004288);      // packed frags           131,072 B
  float* bqk  = (float*)(ws + 21135360);    // [64] f32                   256 B

  prep_weights<<<256, 256, 0, stream>>>(Wq, bq, Wk, bk, Wv, Wqkf, Wvf, bqk);
  fused_proj<<<dim3(64, 8), 256, 0, stream>>>(x, Wqkf, Wvf, bqk, bv, qbuf, kbuf, vbuf);
  attn_fused<<<dim3(8, 32, 2), 256, 0, stream>>>(qbuf, kbuf, vbuf, x, gamma, out);
}

// Round 14
// 112.636 us; speedup vs baseline: 1.1276x; 1.1121x over previous
//
#include <hip/hip_runtime.h>
#include <hip/hip_bf16.h>

#define NB 8
#define CH 256
#define NN 4096
#define CQK 32
#define LOG2E 1.4426950408889634f

typedef __attribute__((ext_vector_type(4))) float f32x4;
typedef __attribute__((ext_vector_type(8))) short bf16x8;
typedef unsigned short u16;

static __device__ __forceinline__ u16 f2bf(float f) {
  unsigned int u = __float_as_uint(f);
  unsigned int r = (u + 0x7fffu + ((u >> 16) & 1u)) >> 16;
  return (u16)r;
}

// ---------------------------------------------------------------------------
// Kernel 1: weights -> bf16, FRAGMENT-PACKED (contiguous 1KB wave loads).
// ---------------------------------------------------------------------------
__global__ void prep_weights(const float* __restrict__ Wq, const float* __restrict__ bq,
                             const float* __restrict__ Wk, const float* __restrict__ bk,
                             const float* __restrict__ Wv,
                             u16* __restrict__ Wqkf, u16* __restrict__ Wvf,
                             float* __restrict__ bqk) {
  int i = blockIdx.x * 256 + threadIdx.x;   // 65536
  int o = i >> 8, c = i & 255;
  int kk = c >> 5, g2 = (c >> 3) & 3, j = c & 7;
  if (o < 64) {
    float wv = (o < 32) ? Wq[o * 256 + c] * LOG2E : Wk[(o - 32) * 256 + c];
    Wqkf[((((o >> 4) * 8 + kk) * 4 + g2) * 16 + (o & 15)) * 8 + j] = f2bf(wv);
  }
  Wvf[((((o >> 4) * 8 + kk) * 4 + g2) * 16 + (o & 15)) * 8 + j] = f2bf(Wv[i]);
  if (i < 64) bqk[i] = (i < 32) ? bq[i] * LOG2E : bk[i - 32];
}

// ---------------------------------------------------------------------------
// Kernel 2: FUSED transpose + both projections (r11, unchanged — verified).
// ---------------------------------------------------------------------------
__global__ __launch_bounds__(256, 2) void fused_proj(
    const float* __restrict__ x, const u16* __restrict__ Wqkf,
    const u16* __restrict__ Wvf, const float* __restrict__ bqk,
    const float* __restrict__ bv,
    u16* __restrict__ qbuf, u16* __restrict__ kbuf, u16* __restrict__ vbuf) {
  __shared__ __align__(128) char xt[64 * 512];
  const int b = blockIdx.y, n0 = blockIdx.x * 64;
  const int tid = threadIdx.x, w = tid >> 6, l = tid & 63, g = l >> 4, lr = l & 15;
  const f32x4 fzero = {0.f, 0.f, 0.f, 0.f};

  {
    const int nl = l, cl = w;
    const float* xp = x + (size_t)b * CH * NN + n0 + nl;
    char* xrow = xt + nl * 512;
    const int swz = (nl & 15) << 4;
#pragma unroll
    for (int p = 0; p < 32; ++p) {
      const int c = p * 8 + cl * 2;
      float f0 = xp[(size_t)c * NN], f1 = xp[(size_t)(c + 1) * NN];
      unsigned int pk = (unsigned int)f2bf(f0) | ((unsigned int)f2bf(f1) << 16);
      *(unsigned int*)(xrow + ((c * 2) ^ swz)) = pk;
    }
  }
  __syncthreads();

  const int aswz = lr << 4;

  {
    f32x4 acc[4];
#pragma unroll
    for (int ct = 0; ct < 4; ++ct) acc[ct] = fzero;
#pragma unroll
    for (int kk = 0; kk < 8; ++kk) {
      bf16x8 af = *(const bf16x8*)(xt + (w * 16 + lr) * 512 + ((kk * 64 + g * 16) ^ aswz));
#pragma unroll
      for (int ct = 0; ct < 4; ++ct) {
        bf16x8 bf = *(const bf16x8*)(Wqkf + (size_t)(((ct * 8 + kk) * 4 + g) * 16 + lr) * 8);
        acc[ct] = __builtin_amdgcn_mfma_f32_16x16x32_bf16(af, bf, acc[ct], 0, 0, 0);
      }
    }
#pragma unroll
    for (int ct = 0; ct < 4; ++ct) {
      const int col = ct * 16 + lr;
      const float bc = bqk[col];
#pragma unroll
      for (int r = 0; r < 4; ++r) {
        const int row = n0 + w * 16 + g * 4 + r;
        u16 h = f2bf(acc[ct][r] + bc);
        if (col < 32) qbuf[((size_t)(b * NN + row)) * 32 + col] = h;
        else          kbuf[((size_t)(b * NN + row)) * 32 + (col - 32)] = h;
      }
    }
  }

  {
    f32x4 vacc[4][4];
#pragma unroll
    for (int ct = 0; ct < 4; ++ct)
#pragma unroll
      for (int mt = 0; mt < 4; ++mt) vacc[ct][mt] = fzero;
#pragma unroll
    for (int kk = 0; kk < 8; ++kk) {
      bf16x8 bfm[4];
#pragma unroll
      for (int mt = 0; mt < 4; ++mt)
        bfm[mt] = *(const bf16x8*)(xt + (mt * 16 + lr) * 512 + ((kk * 64 + g * 16) ^ aswz));
#pragma unroll
      for (int ct = 0; ct < 4; ++ct) {
        bf16x8 af = *(const bf16x8*)(Wvf + (size_t)((((w * 4 + ct) * 8 + kk) * 4 + g) * 16 + lr) * 8);
#pragma unroll
        for (int mt = 0; mt < 4; ++mt)
          vacc[ct][mt] = __builtin_amdgcn_mfma_f32_16x16x32_bf16(af, bfm[mt], vacc[ct][mt], 0, 0, 0);
      }
    }
#pragma unroll
    for (int ct = 0; ct < 4; ++ct) {
#pragma unroll
      for (int mt = 0; mt < 4; ++mt) {
        const int m = n0 + mt * 16 + lr;
#pragma unroll
        for (int r = 0; r < 4; ++r) {
          const int ch = w * 64 + ct * 16 + g * 4 + r;
          vbuf[((size_t)(b * 128 + (m >> 5)) * 256 + ch) * 32 + (m & 31)] = f2bf(vacc[ct][mt][r] + bv[ch]);
        }
      }
    }
  }
}

// ---------------------------------------------------------------------------
// Kernel 3: fused attention = r10's proven dataflow (128q blocks, 8 waves,
// wave w: QK^T+softmax for own 16-q tile, PV for 32-ch slice x 128 q) with
// BK=128: TWO 64-m tiles per barrier -> 32 barriers instead of 64. The
// convoy cost (drain + wave skew at each barrier, the dominant unexplained
// per-iter term) is paid half as often, and the scheduler gets 2x longer
// regions to overlap exp/VALU with MFMA.
// P tile [128q][128m] bf16 (256B rows), XOR swizzle byte^=(row&7)<<4;
// double-buffered (64KB). K ping-pong registers; V loaded h0 pre-barrier,
// h1 post-barrier (covered by 32 MFMAs). setprio around PV cluster.
// ---------------------------------------------------------------------------
#define KLOAD2(T, sub) (*(const bf16x8*)(kp + (size_t)((((T) & 31) * 128) + (sub) * 16) * 32))
#define VLOAD(mg, ct) (*(const bf16x8*)(vp + (size_t)((mg) & 127) * 8192 + (ct) * 512))

#define EXPP(S, PW, MASK) {                                                                   \
  float e0 = __builtin_amdgcn_exp2f(S[0]);                                                    \
  float e1 = __builtin_amdgcn_exp2f(S[1]);                                                    \
  float e2 = __builtin_amdgcn_exp2f(S[2]);                                                    \
  float e3 = __builtin_amdgcn_exp2f(S[3]);                                                    \
  lsum += (MASK) * ((e0 + e1) + (e2 + e3));                                                   \
  PW.x = __builtin_amdgcn_perm(__float_as_uint(e1) + 0x8000u, __float_as_uint(e0) + 0x8000u, 0x07060302u); \
  PW.y = __builtin_amdgcn_perm(__float_as_uint(e3) + 0x8000u, __float_as_uint(e2) + 0x8000u, 0x07060302u); \
}

#define PBAR() do {                                  \
  __builtin_amdgcn_sched_barrier(0);                 \
  asm volatile("s_waitcnt lgkmcnt(0)");              \
  __builtin_amdgcn_s_barrier();                      \
  __builtin_amdgcn_sched_barrier(0);                 \
} while (0)

// 8 QK MFMAs for the next step's P, into pw0..7
#define QK8(K0, K1, K2, K3, K4, K5, K6, K7, MASK) {                                           \
  f32x4 s0 = __builtin_amdgcn_mfma_f32_16x16x32_bf16(K0, qf, fzero, 0, 0, 0);                 \
  f32x4 s1 = __builtin_amdgcn_mfma_f32_16x16x32_bf16(K1, qf, fzero, 0, 0, 0);                 \
  f32x4 s2 = __builtin_amdgcn_mfma_f32_16x16x32_bf16(K2, qf, fzero, 0, 0, 0);                 \
  f32x4 s3 = __builtin_amdgcn_mfma_f32_16x16x32_bf16(K3, qf, fzero, 0, 0, 0);                 \
  f32x4 s4 = __builtin_amdgcn_mfma_f32_16x16x32_bf16(K4, qf, fzero, 0, 0, 0);                 \
  f32x4 s5 = __builtin_amdgcn_mfma_f32_16x16x32_bf16(K5, qf, fzero, 0, 0, 0);                 \
  f32x4 s6 = __builtin_amdgcn_mfma_f32_16x16x32_bf16(K6, qf, fzero, 0, 0, 0);                 \
  f32x4 s7 = __builtin_amdgcn_mfma_f32_16x16x32_bf16(K7, qf, fzero, 0, 0, 0);                 \
  EXPP(s0, pw0, MASK); EXPP(s1, pw1, MASK); EXPP(s2, pw2, MASK); EXPP(s3, pw3, MASK);         \
  EXPP(s4, pw4, MASK); EXPP(s5, pw5, MASK); EXPP(s6, pw6, MASK); EXPP(s7, pw7, MASK);         \
}

#define PWRITE(BUF) {                                                                         \
  char* pdst = (char*)Pb + (BUF) * 32768 + prow * 256;                                        \
  *(uint2*)(pdst + ((0 * 32 + g * 8) ^ wswz)) = pw0;                                          \
  *(uint2*)(pdst + ((1 * 32 + g * 8) ^ wswz)) = pw1;                                          \
  *(uint2*)(pdst + ((2 * 32 + g * 8) ^ wswz)) = pw2;                                          \
  *(uint2*)(pdst + ((3 * 32 + g * 8) ^ wswz)) = pw3;                                          \
  *(uint2*)(pdst + ((4 * 32 + g * 8) ^ wswz)) = pw4;                                          \
  *(uint2*)(pdst + ((5 * 32 + g * 8) ^ wswz)) = pw5;                                          \
  *(uint2*)(pdst + ((6 * 32 + g * 8) ^ wswz)) = pw6;                                          \
  *(uint2*)(pdst + ((7 * 32 + g * 8) ^ wswz)) = pw7;                                          \
}

// one 32-m quarter: 8 q-subtiles x (1 b128 P-read + 2 MFMA)
#define PVQ(PRB, QTR, VA, VB) {                                                               \
  _Pragma("unroll")                                                                           \
  for (int nt = 0; nt < 8; ++nt) {                                                            \
    const int row = nt * 16 + lr;                                                             \
    const int rs = (row & 7) << 4;                                                            \
    bf16x8 pa = *(const bf16x8*)((PRB) + row * 256 + (((QTR) * 64 + g * 16) ^ rs));           \
    oacc[nt][0] = __builtin_amdgcn_mfma_f32_16x16x32_bf16(VA, pa, oacc[nt][0], 0, 0, 0);      \
    oacc[nt][1] = __builtin_amdgcn_mfma_f32_16x16x32_bf16(VB, pa, oacc[nt][1], 0, 0, 0);      \
  }                                                                                           \
}

__global__ __launch_bounds__(512, 2) void attn_fused(
    const u16* __restrict__ qb, const u16* __restrict__ kbuf,
    const u16* __restrict__ vbuf, const float* __restrict__ x,
    const float* __restrict__ gamma_p, float* __restrict__ out) {
  __shared__ __align__(128) char Pb[2][128 * 256];
  __shared__ float lsum_s[128];

  const int b = blockIdx.x;          // batch -> XCD pinning
  const int n0 = blockIdx.y * 128;
  const int tid = threadIdx.x, w = tid >> 6, l = tid & 63, g = l >> 4, lr = l & 15;
  const float gamma0 = gamma_p[0];
  const f32x4 fzero = {0.f, 0.f, 0.f, 0.f};

  bf16x8 qf = *(const bf16x8*)(qb + ((size_t)b * NN + n0 + w * 16 + lr) * 32 + g * 8);

  const u16* kp = kbuf + (size_t)b * (NN * 32) + (size_t)lr * 32 + g * 8;
  const u16* vp = vbuf + (size_t)b * 1048576 + (size_t)(w * 32 + lr) * 32 + g * 8;

  f32x4 oacc[8][2];
#pragma unroll
  for (int nt = 0; nt < 8; ++nt)
#pragma unroll
    for (int ct = 0; ct < 2; ++ct) oacc[nt][ct] = fzero;
  float lsum = 0.f;

  const int prow = w * 16 + lr;
  const int wswz = (prow & 7) << 4;

  // ---- prologue: K(0)->kA, K(1)->kB; compute P(0) -> Pb[0] ----
  bf16x8 kA0 = KLOAD2(0, 0), kA1 = KLOAD2(0, 1), kA2 = KLOAD2(0, 2), kA3 = KLOAD2(0, 3);
  bf16x8 kA4 = KLOAD2(0, 4), kA5 = KLOAD2(0, 5), kA6 = KLOAD2(0, 6), kA7 = KLOAD2(0, 7);
  bf16x8 kB0 = KLOAD2(1, 0), kB1 = KLOAD2(1, 1), kB2 = KLOAD2(1, 2), kB3 = KLOAD2(1, 3);
  bf16x8 kB4 = KLOAD2(1, 4), kB5 = KLOAD2(1, 5), kB6 = KLOAD2(1, 6), kB7 = KLOAD2(1, 7);
  bf16x8 v0, v1, v2, v3, v4, v5, v6, v7;
  uint2 pw0, pw1, pw2, pw3, pw4, pw5, pw6, pw7;
  QK8(kA0, kA1, kA2, kA3, kA4, kA5, kA6, kA7, 1.0f);
  PWRITE(0);

  for (int T2 = 0; T2 < 16; ++T2) {
    // ===== step T = 2*T2 (even): consume Pb[0]; prepare P(T+1) -> Pb[1] =====
    {
      const int T = 2 * T2;
      // pre-barrier: QK(T+1) with kB; load kA = K(T+2); V h0 of step T
      v0 = VLOAD(4 * T, 0); v1 = VLOAD(4 * T, 1);
      v2 = VLOAD(4 * T + 1, 0); v3 = VLOAD(4 * T + 1, 1);
      QK8(kB0, kB1, kB2, kB3, kB4, kB5, kB6, kB7, 1.0f);
      kA0 = KLOAD2(T + 2, 0); kA1 = KLOAD2(T + 2, 1); kA2 = KLOAD2(T + 2, 2); kA3 = KLOAD2(T + 2, 3);
      kA4 = KLOAD2(T + 2, 4); kA5 = KLOAD2(T + 2, 5); kA6 = KLOAD2(T + 2, 6); kA7 = KLOAD2(T + 2, 7);
      PBAR();
      // post-barrier: write P(T+1); V h1 early; 64 PV MFMA
      PWRITE(1);
      v4 = VLOAD(4 * T + 2, 0); v5 = VLOAD(4 * T + 2, 1);
      v6 = VLOAD(4 * T + 3, 0); v7 = VLOAD(4 * T + 3, 1);
      const char* prb = (const char*)Pb;
      __builtin_amdgcn_s_setprio(1);
      PVQ(prb, 0, v0, v1);
      PVQ(prb, 1, v2, v3);
      PVQ(prb, 2, v4, v5);
      PVQ(prb, 3, v6, v7);
      __builtin_amdgcn_s_setprio(0);
    }
    // ===== step T = 2*T2+1 (odd): consume Pb[1]; prepare P(T+1) -> Pb[0] =====
    {
      const int T = 2 * T2 + 1;
      const float tmask = (T2 < 15) ? 1.0f : 0.0f;  // P(32) wraps: exclude
      v0 = VLOAD(4 * T, 0); v1 = VLOAD(4 * T, 1);
      v2 = VLOAD(4 * T + 1, 0); v3 = VLOAD(4 * T + 1, 1);
      QK8(kA0, kA1, kA2, kA3, kA4, kA5, kA6, kA7, tmask);
      kB0 = KLOAD2(T + 2, 0); kB1 = KLOAD2(T + 2, 1); kB2 = KLOAD2(T + 2, 2); kB3 = KLOAD2(T + 2, 3);
      kB4 = KLOAD2(T + 2, 4); kB5 = KLOAD2(T + 2, 5); kB6 = KLOAD2(T + 2, 6); kB7 = KLOAD2(T + 2, 7);
      PBAR();
      PWRITE(0);
      v4 = VLOAD(4 * T + 2, 0); v5 = VLOAD(4 * T + 2, 1);
      v6 = VLOAD(4 * T + 3, 0); v7 = VLOAD(4 * T + 3, 1);
      const char* prb = (const char*)Pb + 32768;
      __builtin_amdgcn_s_setprio(1);
      PVQ(prb, 0, v0, v1);
      PVQ(prb, 1, v2, v3);
      PVQ(prb, 2, v4, v5);
      PVQ(prb, 3, v6, v7);
      __builtin_amdgcn_s_setprio(0);
    }
  }

  // ---- epilogue: share lsum, normalize, gamma*O + x ----
  lsum += __shfl_xor(lsum, 16);
  lsum += __shfl_xor(lsum, 32);
  if (l < 16) lsum_s[w * 16 + lr] = lsum;
  __syncthreads();

  const size_t bbase = (size_t)b * CH * NN;
#pragma unroll
  for (int nt = 0; nt < 8; ++nt) {
    const int q = nt * 16 + lr;
    const float linv = 1.f / lsum_s[q];
    const int n = n0 + q;
#pragma unroll
    for (int ct = 0; ct < 2; ++ct) {
      const int cbase = w * 32 + ct * 16 + g * 4;
#pragma unroll
      for (int r = 0; r < 4; ++r) {
        const size_t off = bbase + (size_t)(cbase + r) * NN + n;
        out[off] = gamma0 * (oacc[nt][ct][r] * linv) + x[off];
      }
    }
  }
}

// ---------------------------------------------------------------------------
extern "C" void kernel_launch(void* const* d_in, const int* in_sizes, int n_in,
                              void* d_out, int out_size, void* d_ws, size_t ws_size,
                              hipStream_t stream) {
  const float* x     = (const float*)d_in[0];
  const float* Wq    = (const float*)d_in[1];
  const float* bq    = (const float*)d_in[2];
  const float* Wk    = (const float*)d_in[3];
  const float* bk    = (const float*)d_in[4];
  const float* Wv    = (const float*)d_in[5];
  const float* bv    = (const float*)d_in[6];
  const float* gamma = (const float*)d_in[7];
  float* out = (float*)d_out;

  char* ws = (char*)d_ws;
  u16*   qbuf = (u16*)(ws);                 // [B,N,32] packed      2,097,152 B
  u16*   kbuf = (u16*)(ws + 2097152);       // [B,N,32] packed      2,097,152 B
  u16*   vbuf = (u16*)(ws + 4194304);       // v fragments         16,777,216 B
  u16*   Wqkf = (u16*)(ws + 20971520);      // packed frags            32,768 B
  u16*   Wvf  = (u16*)(ws + 21004288);      // packed frags           131,072 B
  float* bqk  = (float*)(ws + 21135360);    // [64] f32                   256 B

  prep_weights<<<256, 256, 0, stream>>>(Wq, bq, Wk, bk, Wv, Wqkf, Wvf, bqk);
  fused_proj<<<dim3(64, 8), 256, 0, stream>>>(x, Wqkf, Wvf, bqk, bv, qbuf, kbuf, vbuf);
  attn_fused<<<dim3(8, 32), 512, 0, stream>>>(qbuf, kbuf, vbuf, x, gamma, out);
}